// Round 11
// baseline (70.571 us; speedup 1.0000x reference)
//
#include <hip/hip_runtime.h>
#include <math.h>

#define NB 16
#define NC 128
#define NHW 4096     // 64*64
#define NHWP 1024    // 32*32
#define NCQ 16       // C/8
#define NCV 64       // C/2
#define L2E 1.44269504f

typedef __attribute__((ext_vector_type(8))) short short8;
typedef __attribute__((ext_vector_type(4))) float f32x4;

__device__ inline unsigned short f2bf(float f) {
  unsigned u = __builtin_bit_cast(unsigned, f);
  u += 0x7fffu + ((u >> 16) & 1u);          // RNE
  return (unsigned short)(u >> 16);
}

__device__ inline unsigned pk2(float lo, float hi) {
  unsigned r;
  asm("v_cvt_pk_bf16_f32 %0, %1, %2" : "=v"(r) : "v"(lo), "v"(hi));
  return r;
}

// XCD-aware chunked swizzle (grids are multiples of 8)
__device__ inline int xcd_swz(int bid, int nwg) {
  int cpx = nwg >> 3;
  return (bid & 7) * cpx + (bid >> 3);
}

// ---------------- fused pool + k,v proj, og-split (5) x mt (16) x cg-split (4)
// outputs: kT bf16 [b][m][16], vv bf16 [b][c][m]
// blocks lbid==0/1 additionally convert wq (x log2e) and wa to bf16.
__global__ __launch_bounds__(256) void projkv_kernel(const float* __restrict__ x,
    const float* __restrict__ wk, const float* __restrict__ bk,
    const float* __restrict__ wv, const float* __restrict__ bv,
    const float* __restrict__ wq, const float* __restrict__ wa,
    unsigned short* __restrict__ kT, unsigned short* __restrict__ vv,
    unsigned short* __restrict__ wqB, unsigned short* __restrict__ waB) {
  __shared__ float swT[NC][16];     // swT[c][o]
  __shared__ float pacc[3][64][17]; // cg 1..3 partials
  __shared__ float sbias[16];
  int lbid = xcd_swz(blockIdx.x, NB * 5 * 16);
  int tid = threadIdx.x;
  // piggyback weight conversion for the attention megakernel
  if (lbid == 0) {
    for (int i = tid; i < NCQ * NC; i += 256) wqB[i] = f2bf(wq[i] * L2E);
  } else if (lbid == 1) {
    for (int i = tid; i < NC * NCV; i += 256) waB[i] = f2bf(wa[i]);
  }
  int og = lbid % 5;
  int mt = (lbid / 5) & 15;
  int b  = lbid / 80;
  const float* wsrc = (og == 0) ? wk : (wv + (size_t)(og - 1) * 16 * NC);
  const float* bsrc = (og == 0) ? bk : (bv + (og - 1) * 16);
  for (int i = tid; i < NC * 16; i += 256) {
    int o = i >> 7, c = i & 127;
    swT[c][o] = wsrc[i];
  }
  if (tid < 16) sbias[tid] = bsrc[tid];
  __syncthreads();
  int ml = tid & 63, cg = tid >> 6;
  int m = mt * 64 + ml;
  int j = m & 31, i2 = m >> 5;
  const float* xb = x + ((size_t)b * NC + cg * 32) * NHW + (size_t)(2 * i2) * 64 + 2 * j;
  float acc[16];
#pragma unroll
  for (int o = 0; o < 16; o++) acc[o] = 0.f;
#pragma unroll 4
  for (int ci = 0; ci < 32; ci++) {
    int c = cg * 32 + ci;
    const float* xc = xb + (size_t)ci * NHW;
    float2 t0 = *(const float2*)xc;
    float2 t1 = *(const float2*)(xc + 64);
    float xv = fmaxf(fmaxf(t0.x, t0.y), fmaxf(t1.x, t1.y));   // 2x2 maxpool
    const float4* wr = (const float4*)&swT[c][0];
#pragma unroll
    for (int o4 = 0; o4 < 4; o4++) {
      float4 w4 = wr[o4];
      acc[4*o4+0] = fmaf(xv, w4.x, acc[4*o4+0]);
      acc[4*o4+1] = fmaf(xv, w4.y, acc[4*o4+1]);
      acc[4*o4+2] = fmaf(xv, w4.z, acc[4*o4+2]);
      acc[4*o4+3] = fmaf(xv, w4.w, acc[4*o4+3]);
    }
  }
  if (cg > 0) {
#pragma unroll
    for (int o = 0; o < 16; o++) pacc[cg - 1][ml][o] = acc[o];
  }
  __syncthreads();
  if (cg == 0) {
#pragma unroll
    for (int o = 0; o < 16; o++)
      acc[o] += pacc[0][ml][o] + pacc[1][ml][o] + pacc[2][ml][o] + sbias[o];
    if (og == 0) {
      unsigned short* kr = kT + ((size_t)b * NHWP + m) * NCQ;
      uint4 u0, u1;
      u0.x = pk2(acc[0],  acc[1]);  u0.y = pk2(acc[2],  acc[3]);
      u0.z = pk2(acc[4],  acc[5]);  u0.w = pk2(acc[6],  acc[7]);
      u1.x = pk2(acc[8],  acc[9]);  u1.y = pk2(acc[10], acc[11]);
      u1.z = pk2(acc[12], acc[13]); u1.w = pk2(acc[14], acc[15]);
      *(uint4*)kr = u0;
      *(uint4*)(kr + 8) = u1;
    } else {
      unsigned short* vr = vv + (size_t)b * NCV * NHWP + (size_t)(og - 1) * 16 * NHWP + m;
#pragma unroll
      for (int o = 0; o < 16; o++) vr[(size_t)o * NHWP] = f2bf(acc[o]);
    }
  }
}

// ------------- megakernel: Q-proj + attention + outproj + residual
// per block: 64 n. waves (nh,mh): 32n x 512m each, LDS pair-combine,
// feat staged in swizzled LDS, then out = gamma*(wa@feat+ba) + x.
// Main loop: 2-deep software pipeline (K prefetch +2, V prefetch +1,
// scores for chunk i+1 issued before PV of chunk i, exp/pack last).
// Pure reordering of the round-6/10 verified math.
__global__ __launch_bounds__(256) void attn_kernel(const float* __restrict__ x,
    const unsigned short* __restrict__ wqB, const float* __restrict__ bq,
    const unsigned short* __restrict__ kT, const unsigned short* __restrict__ vv,
    const unsigned short* __restrict__ waB, const float* __restrict__ ba,
    const float* __restrict__ gamma, float* __restrict__ out) {
  __shared__ unsigned short qlds[64][32];   // Q^T [n][k] bf16, k16..31 = 0
  __shared__ float sfacc[2][64][37];        // mh=1 partials: 32 facc + 2 esum (odd pad)
  __shared__ unsigned short featlds[64][64];// feat [n][c] bf16, XOR-swizzled
  int tid = threadIdx.x;
  int w = tid >> 6, l = tid & 63, g = l >> 4, n16 = l & 15;
  int nh = w & 1, mh = w >> 1;
  int lbid = xcd_swz(blockIdx.x, NB * 64);
  int b  = lbid >> 6;
  int n0 = (lbid & 63) << 6;                // 64 n per block

  // zero the k=16..31 half of qlds (read by g>=2 B-frags)
  for (int i = tid; i < 64 * 8; i += 256)
    ((unsigned*)&qlds[i >> 3][16])[i & 7] = 0;

  // ---- fused Q projection: wave w computes Q^T[16c x 16n] tile w (wq pre-scaled)
  {
    f32x4 qacc;
#pragma unroll
    for (int r = 0; r < 4; r++) qacc[r] = bq[4 * g + r] * L2E;
#pragma unroll
    for (int s = 0; s < 4; s++) {
      short8 af = *(const short8*)&wqB[n16 * NC + 32 * s + 8 * g];
      const float* xc = x + ((size_t)b * NC + 32 * s + 8 * g) * NHW + n0 + 16 * w + n16;
      float xv[8];
#pragma unroll
      for (int jj = 0; jj < 8; jj++) xv[jj] = xc[(size_t)jj * NHW];
      union { short8 s8; uint4 u4; } bf_;
      bf_.u4.x = pk2(xv[0], xv[1]); bf_.u4.y = pk2(xv[2], xv[3]);
      bf_.u4.z = pk2(xv[4], xv[5]); bf_.u4.w = pk2(xv[6], xv[7]);
      qacc = __builtin_amdgcn_mfma_f32_16x16x32_bf16(af, bf_.s8, qacc, 0, 0, 0);
    }
    unsigned* qw = (unsigned*)&qlds[16 * w + n16][4 * g];
    qw[0] = pk2(qacc[0], qacc[1]);
    qw[1] = pk2(qacc[2], qacc[3]);
  }
  __syncthreads();

  // B-frags: unconditional 16B; g>=2 lanes read the zeroed k-half
  short8 qfA = *(const short8*)&qlds[32 * nh + n16][8 * g];
  short8 qfB = *(const short8*)&qlds[32 * nh + 16 + n16][8 * g];
  short8 ones;
#pragma unroll
  for (int jj = 0; jj < 8; jj++) ones[jj] = (short)0x3F80;

  const unsigned short* kb = kT + (size_t)b * NHWP * NCQ;
  const unsigned short* vb = vv + (size_t)b * NCV * NHWP;
  f32x4 faccA[4], faccB[4];
#pragma unroll
  for (int kt = 0; kt < 4; kt++) {
    faccA[kt] = (f32x4){0.f, 0.f, 0.f, 0.f};
    faccB[kt] = (f32x4){0.f, 0.f, 0.f, 0.f};
  }
  f32x4 esA4 = {0.f, 0.f, 0.f, 0.f}, esB4 = {0.f, 0.f, 0.f, 0.f};
  int mr = 8 * (n16 >> 2) + (n16 & 3);      // sigma remap
  int koff = 8 * (g & 1);                   // g>=2 lanes load junk x zero-B
  int mbase = mh << 9;                      // wave pair's 512-m half

  // ---- pipeline prologue: K(0)+V(0), S(0)->pt(0), K(1) in flight
  short8 a0c = *(const short8*)&kb[(size_t)(mbase + mr) * NCQ + koff];
  short8 a1c = *(const short8*)&kb[(size_t)(mbase + mr + 4) * NCQ + koff];
  short8 vf0 = *(const short8*)&vb[(size_t)(n16)      * NHWP + mbase + 8 * g];
  short8 vf1 = *(const short8*)&vb[(size_t)(16 + n16) * NHWP + mbase + 8 * g];
  short8 vf2 = *(const short8*)&vb[(size_t)(32 + n16) * NHWP + mbase + 8 * g];
  short8 vf3 = *(const short8*)&vb[(size_t)(48 + n16) * NHWP + mbase + 8 * g];
  short8 a0n = *(const short8*)&kb[(size_t)(mbase + 32 + mr) * NCQ + koff];
  short8 a1n = *(const short8*)&kb[(size_t)(mbase + 32 + mr + 4) * NCQ + koff];
  union { short8 s8; uint4 u4; } ptA, ptB;
  {
    f32x4 z = {0.f, 0.f, 0.f, 0.f};
    f32x4 s0A = __builtin_amdgcn_mfma_f32_16x16x32_bf16(a0c, qfA, z, 0, 0, 0);
    f32x4 s1A = __builtin_amdgcn_mfma_f32_16x16x32_bf16(a1c, qfA, z, 0, 0, 0);
    f32x4 s0B = __builtin_amdgcn_mfma_f32_16x16x32_bf16(a0c, qfB, z, 0, 0, 0);
    f32x4 s1B = __builtin_amdgcn_mfma_f32_16x16x32_bf16(a1c, qfB, z, 0, 0, 0);
    float eA0 = __builtin_amdgcn_exp2f(s0A[0]), eA1 = __builtin_amdgcn_exp2f(s0A[1]);
    float eA2 = __builtin_amdgcn_exp2f(s0A[2]), eA3 = __builtin_amdgcn_exp2f(s0A[3]);
    float eA4 = __builtin_amdgcn_exp2f(s1A[0]), eA5 = __builtin_amdgcn_exp2f(s1A[1]);
    float eA6 = __builtin_amdgcn_exp2f(s1A[2]), eA7 = __builtin_amdgcn_exp2f(s1A[3]);
    float eB0 = __builtin_amdgcn_exp2f(s0B[0]), eB1 = __builtin_amdgcn_exp2f(s0B[1]);
    float eB2 = __builtin_amdgcn_exp2f(s0B[2]), eB3 = __builtin_amdgcn_exp2f(s0B[3]);
    float eB4 = __builtin_amdgcn_exp2f(s1B[0]), eB5 = __builtin_amdgcn_exp2f(s1B[1]);
    float eB6 = __builtin_amdgcn_exp2f(s1B[2]), eB7 = __builtin_amdgcn_exp2f(s1B[3]);
    ptA.u4.x = pk2(eA0, eA1); ptA.u4.y = pk2(eA2, eA3);
    ptA.u4.z = pk2(eA4, eA5); ptA.u4.w = pk2(eA6, eA7);
    ptB.u4.x = pk2(eB0, eB1); ptB.u4.y = pk2(eB2, eB3);
    ptB.u4.z = pk2(eB4, eB5); ptB.u4.w = pk2(eB6, eB7);
  }

#pragma unroll 2
  for (int mi = 0; mi < 16; mi++) {
    int m1 = mbase + 32 * ((mi + 1) & 15);
    int m2 = mbase + 32 * ((mi + 2) & 15);
    // prefetch K(i+2), V(i+1) — consumed next iteration
    short8 a0f = *(const short8*)&kb[(size_t)(m2 + mr) * NCQ + koff];
    short8 a1f = *(const short8*)&kb[(size_t)(m2 + mr + 4) * NCQ + koff];
    short8 vg0 = *(const short8*)&vb[(size_t)(n16)      * NHWP + m1 + 8 * g];
    short8 vg1 = *(const short8*)&vb[(size_t)(16 + n16) * NHWP + m1 + 8 * g];
    short8 vg2 = *(const short8*)&vb[(size_t)(32 + n16) * NHWP + m1 + 8 * g];
    short8 vg3 = *(const short8*)&vb[(size_t)(48 + n16) * NHWP + m1 + 8 * g];
    // scores for chunk i+1 (operands prefetched one iteration ago)
    f32x4 z = {0.f, 0.f, 0.f, 0.f};
    __builtin_amdgcn_s_setprio(1);
    f32x4 s0A = __builtin_amdgcn_mfma_f32_16x16x32_bf16(a0n, qfA, z, 0, 0, 0);
    f32x4 s1A = __builtin_amdgcn_mfma_f32_16x16x32_bf16(a1n, qfA, z, 0, 0, 0);
    f32x4 s0B = __builtin_amdgcn_mfma_f32_16x16x32_bf16(a0n, qfB, z, 0, 0, 0);
    f32x4 s1B = __builtin_amdgcn_mfma_f32_16x16x32_bf16(a1n, qfB, z, 0, 0, 0);
    // PV for chunk i (covers the score-MFMA latency)
    esA4 = __builtin_amdgcn_mfma_f32_16x16x32_bf16(ones, ptA.s8, esA4, 0, 0, 0);
    esB4 = __builtin_amdgcn_mfma_f32_16x16x32_bf16(ones, ptB.s8, esB4, 0, 0, 0);
    faccA[0] = __builtin_amdgcn_mfma_f32_16x16x32_bf16(vf0, ptA.s8, faccA[0], 0, 0, 0);
    faccB[0] = __builtin_amdgcn_mfma_f32_16x16x32_bf16(vf0, ptB.s8, faccB[0], 0, 0, 0);
    faccA[1] = __builtin_amdgcn_mfma_f32_16x16x32_bf16(vf1, ptA.s8, faccA[1], 0, 0, 0);
    faccB[1] = __builtin_amdgcn_mfma_f32_16x16x32_bf16(vf1, ptB.s8, faccB[1], 0, 0, 0);
    faccA[2] = __builtin_amdgcn_mfma_f32_16x16x32_bf16(vf2, ptA.s8, faccA[2], 0, 0, 0);
    faccB[2] = __builtin_amdgcn_mfma_f32_16x16x32_bf16(vf2, ptB.s8, faccB[2], 0, 0, 0);
    faccA[3] = __builtin_amdgcn_mfma_f32_16x16x32_bf16(vf3, ptA.s8, faccA[3], 0, 0, 0);
    faccB[3] = __builtin_amdgcn_mfma_f32_16x16x32_bf16(vf3, ptB.s8, faccB[3], 0, 0, 0);
    __builtin_amdgcn_s_setprio(0);
    // exp/pack for chunk i+1 (overwrites pt AFTER PV consumed it)
    float eA0 = __builtin_amdgcn_exp2f(s0A[0]), eA1 = __builtin_amdgcn_exp2f(s0A[1]);
    float eA2 = __builtin_amdgcn_exp2f(s0A[2]), eA3 = __builtin_amdgcn_exp2f(s0A[3]);
    float eA4 = __builtin_amdgcn_exp2f(s1A[0]), eA5 = __builtin_amdgcn_exp2f(s1A[1]);
    float eA6 = __builtin_amdgcn_exp2f(s1A[2]), eA7 = __builtin_amdgcn_exp2f(s1A[3]);
    float eB0 = __builtin_amdgcn_exp2f(s0B[0]), eB1 = __builtin_amdgcn_exp2f(s0B[1]);
    float eB2 = __builtin_amdgcn_exp2f(s0B[2]), eB3 = __builtin_amdgcn_exp2f(s0B[3]);
    float eB4 = __builtin_amdgcn_exp2f(s1B[0]), eB5 = __builtin_amdgcn_exp2f(s1B[1]);
    float eB6 = __builtin_amdgcn_exp2f(s1B[2]), eB7 = __builtin_amdgcn_exp2f(s1B[3]);
    ptA.u4.x = pk2(eA0, eA1); ptA.u4.y = pk2(eA2, eA3);
    ptA.u4.z = pk2(eA4, eA5); ptA.u4.w = pk2(eA6, eA7);
    ptB.u4.x = pk2(eB0, eB1); ptB.u4.y = pk2(eB2, eB3);
    ptB.u4.z = pk2(eB4, eB5); ptB.u4.w = pk2(eB6, eB7);
    // rotate pipeline registers (static names, unroll makes copies free)
    a0n = a0f; a1n = a1f;
    vf0 = vg0; vf1 = vg1; vf2 = vg2; vf3 = vg3;
  }

  // ---- pair combine: mh=1 waves dump, mh=0 waves finalize into featlds
  if (mh == 1) {
#pragma unroll
    for (int kt = 0; kt < 4; kt++)
#pragma unroll
      for (int r = 0; r < 4; r++) {
        sfacc[nh][l][4 * kt + r]      = faccA[kt][r];
        sfacc[nh][l][16 + 4 * kt + r] = faccB[kt][r];
      }
    sfacc[nh][l][32] = esA4[0];
    sfacc[nh][l][33] = esB4[0];
  }
  __syncthreads();
  if (mh == 0) {
    float teA = esA4[0] + sfacc[nh][l][32];
    float teB = esB4[0] + sfacc[nh][l][33];
#pragma unroll
    for (int kt = 0; kt < 4; kt++)
#pragma unroll
      for (int r = 0; r < 4; r++) {
        faccA[kt][r] += sfacc[nh][l][4 * kt + r];
        faccB[kt][r] += sfacc[nh][l][16 + 4 * kt + r];
      }
    float invA = 1.0f / teA, invB = 1.0f / teB;
    int na = 32 * nh + n16, nbw = na + 16;
    char* rowa = (char*)&featlds[0][0] + na * 128;
    char* rowb = (char*)&featlds[0][0] + nbw * 128;
    int rxa = (na & 7) << 4, rxb = (nbw & 7) << 4;
#pragma unroll
    for (int kt = 0; kt < 4; kt++) {
      uint2 ua, ub;
      ua.x = pk2(faccA[kt][0] * invA, faccA[kt][1] * invA);
      ua.y = pk2(faccA[kt][2] * invA, faccA[kt][3] * invA);
      ub.x = pk2(faccB[kt][0] * invB, faccB[kt][1] * invB);
      ub.y = pk2(faccB[kt][2] * invB, faccB[kt][3] * invB);
      int cb = (16 * kt + 4 * g) * 2;
      *(uint2*)(rowa + (cb ^ rxa)) = ua;
      *(uint2*)(rowb + (cb ^ rxb)) = ub;
    }
  }
  __syncthreads();

  // ---- fused outproj: out[128oc][64n] = gamma*(wa@feat + ba) + x
  short8 bfr[4][2];
#pragma unroll
  for (int nt = 0; nt < 4; nt++) {
    int nl = 16 * nt + n16;
    char* rowp = (char*)&featlds[0][0] + nl * 128;
    int rx = (nl & 7) << 4;
#pragma unroll
    for (int s = 0; s < 2; s++)
      bfr[nt][s] = *(const short8*)(rowp + (((32 * s + 8 * g) * 2) ^ rx));
  }
  float g0 = gamma[0];
#pragma unroll
  for (int ti = 0; ti < 2; ti++) {
    int ot = 2 * w + ti;
    short8 af0 = *(const short8*)&waB[(size_t)(16 * ot + n16) * NCV + 8 * g];
    short8 af1 = *(const short8*)&waB[(size_t)(16 * ot + n16) * NCV + 32 + 8 * g];
    float b0 = ba[16 * ot + 4 * g + 0];
    float b1 = ba[16 * ot + 4 * g + 1];
    float b2 = ba[16 * ot + 4 * g + 2];
    float b3 = ba[16 * ot + 4 * g + 3];
#pragma unroll
    for (int nt = 0; nt < 4; nt++) {
      f32x4 c0 = {b0, b1, b2, b3};
      c0 = __builtin_amdgcn_mfma_f32_16x16x32_bf16(af0, bfr[nt][0], c0, 0, 0, 0);
      c0 = __builtin_amdgcn_mfma_f32_16x16x32_bf16(af1, bfr[nt][1], c0, 0, 0, 0);
#pragma unroll
      for (int r = 0; r < 4; r++) {
        size_t idx = ((size_t)b * NC + 16 * ot + 4 * g + r) * NHW + n0 + 16 * nt + n16;
        out[idx] = g0 * c0[r] + x[idx];
      }
    }
  }
}

extern "C" void kernel_launch(void* const* d_in, const int* in_sizes, int n_in,
                              void* d_out, int out_size, void* d_ws, size_t ws_size,
                              hipStream_t stream) {
  const float* x     = (const float*)d_in[0];
  const float* wq    = (const float*)d_in[1];
  const float* bq    = (const float*)d_in[2];
  const float* wk    = (const float*)d_in[3];
  const float* bk    = (const float*)d_in[4];
  const float* wv    = (const float*)d_in[5];
  const float* bv    = (const float*)d_in[6];
  const float* wa    = (const float*)d_in[7];
  const float* ba    = (const float*)d_in[8];
  const float* gamma = (const float*)d_in[9];
  float* out = (float*)d_out;

  unsigned short* kT  = (unsigned short*)d_ws;                 // 16*1024*16  = 512 KB
  unsigned short* vv  = kT + (size_t)NB * NHWP * NCQ;          // 16*64*1024  = 2 MB
  unsigned short* wqB = vv + (size_t)NB * NCV * NHWP;          // 16*128      = 4 KB
  unsigned short* waB = wqB + (size_t)NCQ * NC;                // 128*64      = 16 KB

  projkv_kernel<<<NB * 5 * 16, 256, 0, stream>>>(x, wk, bk, wv, bv, wq, wa,
                                                 kT, vv, wqB, waB);
  attn_kernel  <<<NB * 64,     256, 0, stream>>>(x, wqB, bq, kT, vv, waB, ba,
                                                 gamma, out);
}

// Round 12
// 54.498 us; speedup vs baseline: 1.2949x; 1.2949x over previous
//
#include <hip/hip_runtime.h>
#include <math.h>

#define NB 16
#define NC 128
#define NHW 4096     // 64*64
#define NHWP 1024    // 32*32
#define NCQ 16       // C/8
#define NCV 64       // C/2
#define L2E 1.44269504f

typedef __attribute__((ext_vector_type(8))) short short8;
typedef __attribute__((ext_vector_type(4))) float f32x4;

__device__ inline unsigned short f2bf(float f) {
  unsigned u = __builtin_bit_cast(unsigned, f);
  u += 0x7fffu + ((u >> 16) & 1u);          // RNE
  return (unsigned short)(u >> 16);
}

__device__ inline unsigned pk2(float lo, float hi) {
  unsigned r;
  asm("v_cvt_pk_bf16_f32 %0, %1, %2" : "=v"(r) : "v"(lo), "v"(hi));
  return r;
}

// XCD-aware chunked swizzle (grids are multiples of 8)
__device__ inline int xcd_swz(int bid, int nwg) {
  int cpx = nwg >> 3;
  return (bid & 7) * cpx + (bid >> 3);
}

// ---------------- fused pool + k,v proj, og-split (5) x mt (16) x cg-split (4)
// outputs: kT bf16 [b][m][16], vv bf16 TILED [b][m/32][c][m%32]
// blocks lbid==0/1 additionally convert wq (x log2e) and wa to bf16.
__global__ __launch_bounds__(256) void projkv_kernel(const float* __restrict__ x,
    const float* __restrict__ wk, const float* __restrict__ bk,
    const float* __restrict__ wv, const float* __restrict__ bv,
    const float* __restrict__ wq, const float* __restrict__ wa,
    unsigned short* __restrict__ kT, unsigned short* __restrict__ vv,
    unsigned short* __restrict__ wqB, unsigned short* __restrict__ waB) {
  __shared__ float swT[NC][16];     // swT[c][o]
  __shared__ float pacc[3][64][17]; // cg 1..3 partials
  __shared__ float sbias[16];
  int lbid = xcd_swz(blockIdx.x, NB * 5 * 16);
  int tid = threadIdx.x;
  // piggyback weight conversion for the attention megakernel
  if (lbid == 0) {
    for (int i = tid; i < NCQ * NC; i += 256) wqB[i] = f2bf(wq[i] * L2E);
  } else if (lbid == 1) {
    for (int i = tid; i < NC * NCV; i += 256) waB[i] = f2bf(wa[i]);
  }
  int og = lbid % 5;
  int mt = (lbid / 5) & 15;
  int b  = lbid / 80;
  const float* wsrc = (og == 0) ? wk : (wv + (size_t)(og - 1) * 16 * NC);
  const float* bsrc = (og == 0) ? bk : (bv + (og - 1) * 16);
  for (int i = tid; i < NC * 16; i += 256) {
    int o = i >> 7, c = i & 127;
    swT[c][o] = wsrc[i];
  }
  if (tid < 16) sbias[tid] = bsrc[tid];
  __syncthreads();
  int ml = tid & 63, cg = tid >> 6;
  int m = mt * 64 + ml;
  int j = m & 31, i2 = m >> 5;
  const float* xb = x + ((size_t)b * NC + cg * 32) * NHW + (size_t)(2 * i2) * 64 + 2 * j;
  float acc[16];
#pragma unroll
  for (int o = 0; o < 16; o++) acc[o] = 0.f;
#pragma unroll 4
  for (int ci = 0; ci < 32; ci++) {
    int c = cg * 32 + ci;
    const float* xc = xb + (size_t)ci * NHW;
    float2 t0 = *(const float2*)xc;
    float2 t1 = *(const float2*)(xc + 64);
    float xv = fmaxf(fmaxf(t0.x, t0.y), fmaxf(t1.x, t1.y));   // 2x2 maxpool
    const float4* wr = (const float4*)&swT[c][0];
#pragma unroll
    for (int o4 = 0; o4 < 4; o4++) {
      float4 w4 = wr[o4];
      acc[4*o4+0] = fmaf(xv, w4.x, acc[4*o4+0]);
      acc[4*o4+1] = fmaf(xv, w4.y, acc[4*o4+1]);
      acc[4*o4+2] = fmaf(xv, w4.z, acc[4*o4+2]);
      acc[4*o4+3] = fmaf(xv, w4.w, acc[4*o4+3]);
    }
  }
  if (cg > 0) {
#pragma unroll
    for (int o = 0; o < 16; o++) pacc[cg - 1][ml][o] = acc[o];
  }
  __syncthreads();
  if (cg == 0) {
#pragma unroll
    for (int o = 0; o < 16; o++)
      acc[o] += pacc[0][ml][o] + pacc[1][ml][o] + pacc[2][ml][o] + sbias[o];
    if (og == 0) {
      unsigned short* kr = kT + ((size_t)b * NHWP + m) * NCQ;
      uint4 u0, u1;
      u0.x = pk2(acc[0],  acc[1]);  u0.y = pk2(acc[2],  acc[3]);
      u0.z = pk2(acc[4],  acc[5]);  u0.w = pk2(acc[6],  acc[7]);
      u1.x = pk2(acc[8],  acc[9]);  u1.y = pk2(acc[10], acc[11]);
      u1.z = pk2(acc[12], acc[13]); u1.w = pk2(acc[14], acc[15]);
      *(uint4*)kr = u0;
      *(uint4*)(kr + 8) = u1;
    } else {
      // tiled V: vv[((b*32 + m/32)*NCV + c)*32 + m%32]
      unsigned short* vr = vv + (((size_t)b * 32 + (m >> 5)) * NCV + (og - 1) * 16) * 32
                              + (m & 31);
#pragma unroll
      for (int o = 0; o < 16; o++) vr[(size_t)o * 32] = f2bf(acc[o]);
    }
  }
}

// ------------- megakernel: Q-proj + attention + outproj + residual
// per block: 64 n. waves (nh,mh): 32n x 512m each, LDS pair-combine,
// feat staged in swizzled LDS, then out = gamma*(wa@feat+ba) + x.
// Main loop: round-10 verified structure; V reads from TILED layout so each
// vf load is one dense 1KB segment (was 16 scattered 64B lines).
__global__ __launch_bounds__(256) void attn_kernel(const float* __restrict__ x,
    const unsigned short* __restrict__ wqB, const float* __restrict__ bq,
    const unsigned short* __restrict__ kT, const unsigned short* __restrict__ vv,
    const unsigned short* __restrict__ waB, const float* __restrict__ ba,
    const float* __restrict__ gamma, float* __restrict__ out) {
  __shared__ unsigned short qlds[64][32];   // Q^T [n][k] bf16, k16..31 = 0
  __shared__ float sfacc[2][64][37];        // mh=1 partials: 32 facc + 2 esum (odd pad)
  __shared__ unsigned short featlds[64][64];// feat [n][c] bf16, XOR-swizzled
  int tid = threadIdx.x;
  int w = tid >> 6, l = tid & 63, g = l >> 4, n16 = l & 15;
  int nh = w & 1, mh = w >> 1;
  int lbid = xcd_swz(blockIdx.x, NB * 64);
  int b  = lbid >> 6;
  int n0 = (lbid & 63) << 6;                // 64 n per block

  // zero the k=16..31 half of qlds (read by g>=2 B-frags)
  for (int i = tid; i < 64 * 8; i += 256)
    ((unsigned*)&qlds[i >> 3][16])[i & 7] = 0;

  // ---- fused Q projection: wave w computes Q^T[16c x 16n] tile w (wq pre-scaled)
  {
    f32x4 qacc;
#pragma unroll
    for (int r = 0; r < 4; r++) qacc[r] = bq[4 * g + r] * L2E;
#pragma unroll
    for (int s = 0; s < 4; s++) {
      short8 af = *(const short8*)&wqB[n16 * NC + 32 * s + 8 * g];
      const float* xc = x + ((size_t)b * NC + 32 * s + 8 * g) * NHW + n0 + 16 * w + n16;
      float xv[8];
#pragma unroll
      for (int jj = 0; jj < 8; jj++) xv[jj] = xc[(size_t)jj * NHW];
      union { short8 s8; uint4 u4; } bf_;
      bf_.u4.x = pk2(xv[0], xv[1]); bf_.u4.y = pk2(xv[2], xv[3]);
      bf_.u4.z = pk2(xv[4], xv[5]); bf_.u4.w = pk2(xv[6], xv[7]);
      qacc = __builtin_amdgcn_mfma_f32_16x16x32_bf16(af, bf_.s8, qacc, 0, 0, 0);
    }
    unsigned* qw = (unsigned*)&qlds[16 * w + n16][4 * g];
    qw[0] = pk2(qacc[0], qacc[1]);
    qw[1] = pk2(qacc[2], qacc[3]);
  }
  __syncthreads();

  // B-frags: unconditional 16B; g>=2 lanes read the zeroed k-half
  short8 qfA = *(const short8*)&qlds[32 * nh + n16][8 * g];
  short8 qfB = *(const short8*)&qlds[32 * nh + 16 + n16][8 * g];
  short8 ones;
#pragma unroll
  for (int jj = 0; jj < 8; jj++) ones[jj] = (short)0x3F80;

  const unsigned short* kb = kT + (size_t)b * NHWP * NCQ;
  const unsigned short* vb = vv + (size_t)b * NCV * NHWP;  // tiled base, same extent
  f32x4 faccA[4], faccB[4];
#pragma unroll
  for (int kt = 0; kt < 4; kt++) {
    faccA[kt] = (f32x4){0.f, 0.f, 0.f, 0.f};
    faccB[kt] = (f32x4){0.f, 0.f, 0.f, 0.f};
  }
  f32x4 esA4 = {0.f, 0.f, 0.f, 0.f}, esB4 = {0.f, 0.f, 0.f, 0.f};
  int mr = 8 * (n16 >> 2) + (n16 & 3);      // sigma remap
  int koff = 8 * (g & 1);                   // g>=2 lanes load junk x zero-B
  int mbase = mh << 9;                      // wave pair's 512-m half

#pragma unroll 4
  for (int mi = 0; mi < 16; mi++) {
    int m0 = mbase + 32 * mi;
    // ---- all loads first, unconditional, no exec-mask traffic
    short8 a0 = *(const short8*)&kb[(size_t)(m0 + mr) * NCQ + koff];
    short8 a1 = *(const short8*)&kb[(size_t)(m0 + mr + 4) * NCQ + koff];
    // tiled V: tile (m0>>5) is 64c x 32m contiguous; vf loads are dense 1KB
    const unsigned short* vt = vb + (size_t)(m0 >> 5) * NCV * 32;
    short8 vf0 = *(const short8*)&vt[(n16)      * 32 + 8 * g];
    short8 vf1 = *(const short8*)&vt[(16 + n16) * 32 + 8 * g];
    short8 vf2 = *(const short8*)&vt[(32 + n16) * 32 + 8 * g];
    short8 vf3 = *(const short8*)&vt[(48 + n16) * 32 + 8 * g];
    f32x4 z = {0.f, 0.f, 0.f, 0.f};
    __builtin_amdgcn_s_setprio(1);
    f32x4 s0A = __builtin_amdgcn_mfma_f32_16x16x32_bf16(a0, qfA, z, 0, 0, 0);
    f32x4 s1A = __builtin_amdgcn_mfma_f32_16x16x32_bf16(a1, qfA, z, 0, 0, 0);
    f32x4 s0B = __builtin_amdgcn_mfma_f32_16x16x32_bf16(a0, qfB, z, 0, 0, 0);
    f32x4 s1B = __builtin_amdgcn_mfma_f32_16x16x32_bf16(a1, qfB, z, 0, 0, 0);
    __builtin_amdgcn_s_setprio(0);
    float eA0 = __builtin_amdgcn_exp2f(s0A[0]), eA1 = __builtin_amdgcn_exp2f(s0A[1]);
    float eA2 = __builtin_amdgcn_exp2f(s0A[2]), eA3 = __builtin_amdgcn_exp2f(s0A[3]);
    float eA4 = __builtin_amdgcn_exp2f(s1A[0]), eA5 = __builtin_amdgcn_exp2f(s1A[1]);
    float eA6 = __builtin_amdgcn_exp2f(s1A[2]), eA7 = __builtin_amdgcn_exp2f(s1A[3]);
    float eB0 = __builtin_amdgcn_exp2f(s0B[0]), eB1 = __builtin_amdgcn_exp2f(s0B[1]);
    float eB2 = __builtin_amdgcn_exp2f(s0B[2]), eB3 = __builtin_amdgcn_exp2f(s0B[3]);
    float eB4 = __builtin_amdgcn_exp2f(s1B[0]), eB5 = __builtin_amdgcn_exp2f(s1B[1]);
    float eB6 = __builtin_amdgcn_exp2f(s1B[2]), eB7 = __builtin_amdgcn_exp2f(s1B[3]);
    union { short8 s8; uint4 u4; } ptA, ptB;
    ptA.u4.x = pk2(eA0, eA1); ptA.u4.y = pk2(eA2, eA3);
    ptA.u4.z = pk2(eA4, eA5); ptA.u4.w = pk2(eA6, eA7);
    ptB.u4.x = pk2(eB0, eB1); ptB.u4.y = pk2(eB2, eB3);
    ptB.u4.z = pk2(eB4, eB5); ptB.u4.w = pk2(eB6, eB7);
    __builtin_amdgcn_s_setprio(1);
    esA4 = __builtin_amdgcn_mfma_f32_16x16x32_bf16(ones, ptA.s8, esA4, 0, 0, 0);
    esB4 = __builtin_amdgcn_mfma_f32_16x16x32_bf16(ones, ptB.s8, esB4, 0, 0, 0);
    faccA[0] = __builtin_amdgcn_mfma_f32_16x16x32_bf16(vf0, ptA.s8, faccA[0], 0, 0, 0);
    faccB[0] = __builtin_amdgcn_mfma_f32_16x16x32_bf16(vf0, ptB.s8, faccB[0], 0, 0, 0);
    faccA[1] = __builtin_amdgcn_mfma_f32_16x16x32_bf16(vf1, ptA.s8, faccA[1], 0, 0, 0);
    faccB[1] = __builtin_amdgcn_mfma_f32_16x16x32_bf16(vf1, ptB.s8, faccB[1], 0, 0, 0);
    faccA[2] = __builtin_amdgcn_mfma_f32_16x16x32_bf16(vf2, ptA.s8, faccA[2], 0, 0, 0);
    faccB[2] = __builtin_amdgcn_mfma_f32_16x16x32_bf16(vf2, ptB.s8, faccB[2], 0, 0, 0);
    faccA[3] = __builtin_amdgcn_mfma_f32_16x16x32_bf16(vf3, ptA.s8, faccA[3], 0, 0, 0);
    faccB[3] = __builtin_amdgcn_mfma_f32_16x16x32_bf16(vf3, ptB.s8, faccB[3], 0, 0, 0);
    __builtin_amdgcn_s_setprio(0);
  }

  // ---- pair combine: mh=1 waves dump, mh=0 waves finalize into featlds
  if (mh == 1) {
#pragma unroll
    for (int kt = 0; kt < 4; kt++)
#pragma unroll
      for (int r = 0; r < 4; r++) {
        sfacc[nh][l][4 * kt + r]      = faccA[kt][r];
        sfacc[nh][l][16 + 4 * kt + r] = faccB[kt][r];
      }
    sfacc[nh][l][32] = esA4[0];
    sfacc[nh][l][33] = esB4[0];
  }
  __syncthreads();
  if (mh == 0) {
    float teA = esA4[0] + sfacc[nh][l][32];
    float teB = esB4[0] + sfacc[nh][l][33];
#pragma unroll
    for (int kt = 0; kt < 4; kt++)
#pragma unroll
      for (int r = 0; r < 4; r++) {
        faccA[kt][r] += sfacc[nh][l][4 * kt + r];
        faccB[kt][r] += sfacc[nh][l][16 + 4 * kt + r];
      }
    float invA = 1.0f / teA, invB = 1.0f / teB;
    int na = 32 * nh + n16, nbw = na + 16;
    char* rowa = (char*)&featlds[0][0] + na * 128;
    char* rowb = (char*)&featlds[0][0] + nbw * 128;
    int rxa = (na & 7) << 4, rxb = (nbw & 7) << 4;
#pragma unroll
    for (int kt = 0; kt < 4; kt++) {
      uint2 ua, ub;
      ua.x = pk2(faccA[kt][0] * invA, faccA[kt][1] * invA);
      ua.y = pk2(faccA[kt][2] * invA, faccA[kt][3] * invA);
      ub.x = pk2(faccB[kt][0] * invB, faccB[kt][1] * invB);
      ub.y = pk2(faccB[kt][2] * invB, faccB[kt][3] * invB);
      int cb = (16 * kt + 4 * g) * 2;
      *(uint2*)(rowa + (cb ^ rxa)) = ua;
      *(uint2*)(rowb + (cb ^ rxb)) = ub;
    }
  }
  __syncthreads();

  // ---- fused outproj: out[128oc][64n] = gamma*(wa@feat + ba) + x
  short8 bfr[4][2];
#pragma unroll
  for (int nt = 0; nt < 4; nt++) {
    int nl = 16 * nt + n16;
    char* rowp = (char*)&featlds[0][0] + nl * 128;
    int rx = (nl & 7) << 4;
#pragma unroll
    for (int s = 0; s < 2; s++)
      bfr[nt][s] = *(const short8*)(rowp + (((32 * s + 8 * g) * 2) ^ rx));
  }
  float g0 = gamma[0];
#pragma unroll
  for (int ti = 0; ti < 2; ti++) {
    int ot = 2 * w + ti;
    short8 af0 = *(const short8*)&waB[(size_t)(16 * ot + n16) * NCV + 8 * g];
    short8 af1 = *(const short8*)&waB[(size_t)(16 * ot + n16) * NCV + 32 + 8 * g];
    float b0 = ba[16 * ot + 4 * g + 0];
    float b1 = ba[16 * ot + 4 * g + 1];
    float b2 = ba[16 * ot + 4 * g + 2];
    float b3 = ba[16 * ot + 4 * g + 3];
#pragma unroll
    for (int nt = 0; nt < 4; nt++) {
      f32x4 c0 = {b0, b1, b2, b3};
      c0 = __builtin_amdgcn_mfma_f32_16x16x32_bf16(af0, bfr[nt][0], c0, 0, 0, 0);
      c0 = __builtin_amdgcn_mfma_f32_16x16x32_bf16(af1, bfr[nt][1], c0, 0, 0, 0);
#pragma unroll
      for (int r = 0; r < 4; r++) {
        size_t idx = ((size_t)b * NC + 16 * ot + 4 * g + r) * NHW + n0 + 16 * nt + n16;
        out[idx] = g0 * c0[r] + x[idx];
      }
    }
  }
}

extern "C" void kernel_launch(void* const* d_in, const int* in_sizes, int n_in,
                              void* d_out, int out_size, void* d_ws, size_t ws_size,
                              hipStream_t stream) {
  const float* x     = (const float*)d_in[0];
  const float* wq    = (const float*)d_in[1];
  const float* bq    = (const float*)d_in[2];
  const float* wk    = (const float*)d_in[3];
  const float* bk    = (const float*)d_in[4];
  const float* wv    = (const float*)d_in[5];
  const float* bv    = (const float*)d_in[6];
  const float* wa    = (const float*)d_in[7];
  const float* ba    = (const float*)d_in[8];
  const float* gamma = (const float*)d_in[9];
  float* out = (float*)d_out;

  unsigned short* kT  = (unsigned short*)d_ws;                 // 16*1024*16  = 512 KB
  unsigned short* vv  = kT + (size_t)NB * NHWP * NCQ;          // 16*64*1024  = 2 MB (tiled)
  unsigned short* wqB = vv + (size_t)NB * NCV * NHWP;          // 16*128      = 4 KB
  unsigned short* waB = wqB + (size_t)NCQ * NC;                // 128*64      = 16 KB

  projkv_kernel<<<NB * 5 * 16, 256, 0, stream>>>(x, wk, bk, wv, bv, wq, wa,
                                                 kT, vv, wqB, waB);
  attn_kernel  <<<NB * 64,     256, 0, stream>>>(x, wqB, bq, kT, vv, waB, ba,
                                                 gamma, out);
}

// Round 13
// 50.173 us; speedup vs baseline: 1.4066x; 1.0862x over previous
//
#include <hip/hip_runtime.h>
#include <math.h>

#define NB 16
#define NC 128
#define NHW 4096     // 64*64
#define NHWP 1024    // 32*32
#define NCQ 16       // C/8
#define NCV 64       // C/2
#define L2E 1.44269504f

typedef __attribute__((ext_vector_type(8))) short short8;
typedef __attribute__((ext_vector_type(4))) float f32x4;

__device__ inline unsigned short f2bf(float f) {
  unsigned u = __builtin_bit_cast(unsigned, f);
  u += 0x7fffu + ((u >> 16) & 1u);          // RNE
  return (unsigned short)(u >> 16);
}

__device__ inline unsigned pk2(float lo, float hi) {
  unsigned r;
  asm("v_cvt_pk_bf16_f32 %0, %1, %2" : "=v"(r) : "v"(lo), "v"(hi));
  return r;
}

// XCD-aware chunked swizzle (grids are multiples of 8)
__device__ inline int xcd_swz(int bid, int nwg) {
  int cpx = nwg >> 3;
  return (bid & 7) * cpx + (bid >> 3);
}

// ---------------- fused pool + k,v proj, og-split (5) x mt (16) x cg-split (4)
// outputs: kT bf16 [b][m][16], vv bf16 TILED [b][m/32][c][m%32]
// blocks lbid==0/1 additionally convert wq (x log2e) and wa to bf16.
__global__ __launch_bounds__(256) void projkv_kernel(const float* __restrict__ x,
    const float* __restrict__ wk, const float* __restrict__ bk,
    const float* __restrict__ wv, const float* __restrict__ bv,
    const float* __restrict__ wq, const float* __restrict__ wa,
    unsigned short* __restrict__ kT, unsigned short* __restrict__ vv,
    unsigned short* __restrict__ wqB, unsigned short* __restrict__ waB) {
  __shared__ float swT[NC][16];     // swT[c][o]
  __shared__ float pacc[3][64][17]; // cg 1..3 partials
  __shared__ float sbias[16];
  int lbid = xcd_swz(blockIdx.x, NB * 5 * 16);
  int tid = threadIdx.x;
  // piggyback weight conversion for the attention megakernel
  if (lbid == 0) {
    for (int i = tid; i < NCQ * NC; i += 256) wqB[i] = f2bf(wq[i] * L2E);
  } else if (lbid == 1) {
    for (int i = tid; i < NC * NCV; i += 256) waB[i] = f2bf(wa[i]);
  }
  int og = lbid % 5;
  int mt = (lbid / 5) & 15;
  int b  = lbid / 80;
  const float* wsrc = (og == 0) ? wk : (wv + (size_t)(og - 1) * 16 * NC);
  const float* bsrc = (og == 0) ? bk : (bv + (og - 1) * 16);
  for (int i = tid; i < NC * 16; i += 256) {
    int o = i >> 7, c = i & 127;
    swT[c][o] = wsrc[i];
  }
  if (tid < 16) sbias[tid] = bsrc[tid];
  __syncthreads();
  int ml = tid & 63, cg = tid >> 6;
  int m = mt * 64 + ml;
  int j = m & 31, i2 = m >> 5;
  const float* xb = x + ((size_t)b * NC + cg * 32) * NHW + (size_t)(2 * i2) * 64 + 2 * j;
  float acc[16];
#pragma unroll
  for (int o = 0; o < 16; o++) acc[o] = 0.f;
#pragma unroll 4
  for (int ci = 0; ci < 32; ci++) {
    int c = cg * 32 + ci;
    const float* xc = xb + (size_t)ci * NHW;
    float2 t0 = *(const float2*)xc;
    float2 t1 = *(const float2*)(xc + 64);
    float xv = fmaxf(fmaxf(t0.x, t0.y), fmaxf(t1.x, t1.y));   // 2x2 maxpool
    const float4* wr = (const float4*)&swT[c][0];
#pragma unroll
    for (int o4 = 0; o4 < 4; o4++) {
      float4 w4 = wr[o4];
      acc[4*o4+0] = fmaf(xv, w4.x, acc[4*o4+0]);
      acc[4*o4+1] = fmaf(xv, w4.y, acc[4*o4+1]);
      acc[4*o4+2] = fmaf(xv, w4.z, acc[4*o4+2]);
      acc[4*o4+3] = fmaf(xv, w4.w, acc[4*o4+3]);
    }
  }
  if (cg > 0) {
#pragma unroll
    for (int o = 0; o < 16; o++) pacc[cg - 1][ml][o] = acc[o];
  }
  __syncthreads();
  if (cg == 0) {
#pragma unroll
    for (int o = 0; o < 16; o++)
      acc[o] += pacc[0][ml][o] + pacc[1][ml][o] + pacc[2][ml][o] + sbias[o];
    if (og == 0) {
      unsigned short* kr = kT + ((size_t)b * NHWP + m) * NCQ;
      uint4 u0, u1;
      u0.x = pk2(acc[0],  acc[1]);  u0.y = pk2(acc[2],  acc[3]);
      u0.z = pk2(acc[4],  acc[5]);  u0.w = pk2(acc[6],  acc[7]);
      u1.x = pk2(acc[8],  acc[9]);  u1.y = pk2(acc[10], acc[11]);
      u1.z = pk2(acc[12], acc[13]); u1.w = pk2(acc[14], acc[15]);
      *(uint4*)kr = u0;
      *(uint4*)(kr + 8) = u1;
    } else {
      // tiled V: vv[((b*32 + m/32)*NCV + c)*32 + m%32]
      unsigned short* vr = vv + (((size_t)b * 32 + (m >> 5)) * NCV + (og - 1) * 16) * 32
                              + (m & 31);
#pragma unroll
      for (int o = 0; o < 16; o++) vr[(size_t)o * 32] = f2bf(acc[o]);
    }
  }
}

// ------------- megakernel: Q-proj + attention + outproj + residual
// per block: 64 n. waves (nh,mh): 32n x 512m each, LDS pair-combine,
// feat staged in swizzled LDS, then out = gamma*(wa@feat+ba) + x.
// Main loop: round-12 verified structure (tiled V). launch_bounds(256,4)
// grants the 128-VGPR budget matching the grid's 4 blocks/CU so the
// compiler can hoist next-iteration loads; unroll 8 widens its window.
__global__ __launch_bounds__(256, 4) void attn_kernel(const float* __restrict__ x,
    const unsigned short* __restrict__ wqB, const float* __restrict__ bq,
    const unsigned short* __restrict__ kT, const unsigned short* __restrict__ vv,
    const unsigned short* __restrict__ waB, const float* __restrict__ ba,
    const float* __restrict__ gamma, float* __restrict__ out) {
  __shared__ unsigned short qlds[64][32];   // Q^T [n][k] bf16, k16..31 = 0
  __shared__ float sfacc[2][64][37];        // mh=1 partials: 32 facc + 2 esum (odd pad)
  __shared__ unsigned short featlds[64][64];// feat [n][c] bf16, XOR-swizzled
  int tid = threadIdx.x;
  int w = tid >> 6, l = tid & 63, g = l >> 4, n16 = l & 15;
  int nh = w & 1, mh = w >> 1;
  int lbid = xcd_swz(blockIdx.x, NB * 64);
  int b  = lbid >> 6;
  int n0 = (lbid & 63) << 6;                // 64 n per block

  // zero the k=16..31 half of qlds (read by g>=2 B-frags)
  for (int i = tid; i < 64 * 8; i += 256)
    ((unsigned*)&qlds[i >> 3][16])[i & 7] = 0;

  // ---- fused Q projection: wave w computes Q^T[16c x 16n] tile w (wq pre-scaled)
  {
    f32x4 qacc;
#pragma unroll
    for (int r = 0; r < 4; r++) qacc[r] = bq[4 * g + r] * L2E;
#pragma unroll
    for (int s = 0; s < 4; s++) {
      short8 af = *(const short8*)&wqB[n16 * NC + 32 * s + 8 * g];
      const float* xc = x + ((size_t)b * NC + 32 * s + 8 * g) * NHW + n0 + 16 * w + n16;
      float xv[8];
#pragma unroll
      for (int jj = 0; jj < 8; jj++) xv[jj] = xc[(size_t)jj * NHW];
      union { short8 s8; uint4 u4; } bf_;
      bf_.u4.x = pk2(xv[0], xv[1]); bf_.u4.y = pk2(xv[2], xv[3]);
      bf_.u4.z = pk2(xv[4], xv[5]); bf_.u4.w = pk2(xv[6], xv[7]);
      qacc = __builtin_amdgcn_mfma_f32_16x16x32_bf16(af, bf_.s8, qacc, 0, 0, 0);
    }
    unsigned* qw = (unsigned*)&qlds[16 * w + n16][4 * g];
    qw[0] = pk2(qacc[0], qacc[1]);
    qw[1] = pk2(qacc[2], qacc[3]);
  }
  __syncthreads();

  // B-frags: unconditional 16B; g>=2 lanes read the zeroed k-half
  short8 qfA = *(const short8*)&qlds[32 * nh + n16][8 * g];
  short8 qfB = *(const short8*)&qlds[32 * nh + 16 + n16][8 * g];
  short8 ones;
#pragma unroll
  for (int jj = 0; jj < 8; jj++) ones[jj] = (short)0x3F80;

  const unsigned short* kb = kT + (size_t)b * NHWP * NCQ;
  const unsigned short* vb = vv + (size_t)b * NCV * NHWP;  // tiled base, same extent
  f32x4 faccA[4], faccB[4];
#pragma unroll
  for (int kt = 0; kt < 4; kt++) {
    faccA[kt] = (f32x4){0.f, 0.f, 0.f, 0.f};
    faccB[kt] = (f32x4){0.f, 0.f, 0.f, 0.f};
  }
  f32x4 esA4 = {0.f, 0.f, 0.f, 0.f}, esB4 = {0.f, 0.f, 0.f, 0.f};
  int mr = 8 * (n16 >> 2) + (n16 & 3);      // sigma remap
  int koff = 8 * (g & 1);                   // g>=2 lanes load junk x zero-B
  int mbase = mh << 9;                      // wave pair's 512-m half

#pragma unroll 8
  for (int mi = 0; mi < 16; mi++) {
    int m0 = mbase + 32 * mi;
    // ---- all loads first, unconditional, no exec-mask traffic
    short8 a0 = *(const short8*)&kb[(size_t)(m0 + mr) * NCQ + koff];
    short8 a1 = *(const short8*)&kb[(size_t)(m0 + mr + 4) * NCQ + koff];
    // tiled V: tile (m0>>5) is 64c x 32m contiguous; vf loads are dense 1KB
    const unsigned short* vt = vb + (size_t)(m0 >> 5) * NCV * 32;
    short8 vf0 = *(const short8*)&vt[(n16)      * 32 + 8 * g];
    short8 vf1 = *(const short8*)&vt[(16 + n16) * 32 + 8 * g];
    short8 vf2 = *(const short8*)&vt[(32 + n16) * 32 + 8 * g];
    short8 vf3 = *(const short8*)&vt[(48 + n16) * 32 + 8 * g];
    f32x4 z = {0.f, 0.f, 0.f, 0.f};
    __builtin_amdgcn_s_setprio(1);
    f32x4 s0A = __builtin_amdgcn_mfma_f32_16x16x32_bf16(a0, qfA, z, 0, 0, 0);
    f32x4 s1A = __builtin_amdgcn_mfma_f32_16x16x32_bf16(a1, qfA, z, 0, 0, 0);
    f32x4 s0B = __builtin_amdgcn_mfma_f32_16x16x32_bf16(a0, qfB, z, 0, 0, 0);
    f32x4 s1B = __builtin_amdgcn_mfma_f32_16x16x32_bf16(a1, qfB, z, 0, 0, 0);
    __builtin_amdgcn_s_setprio(0);
    float eA0 = __builtin_amdgcn_exp2f(s0A[0]), eA1 = __builtin_amdgcn_exp2f(s0A[1]);
    float eA2 = __builtin_amdgcn_exp2f(s0A[2]), eA3 = __builtin_amdgcn_exp2f(s0A[3]);
    float eA4 = __builtin_amdgcn_exp2f(s1A[0]), eA5 = __builtin_amdgcn_exp2f(s1A[1]);
    float eA6 = __builtin_amdgcn_exp2f(s1A[2]), eA7 = __builtin_amdgcn_exp2f(s1A[3]);
    float eB0 = __builtin_amdgcn_exp2f(s0B[0]), eB1 = __builtin_amdgcn_exp2f(s0B[1]);
    float eB2 = __builtin_amdgcn_exp2f(s0B[2]), eB3 = __builtin_amdgcn_exp2f(s0B[3]);
    float eB4 = __builtin_amdgcn_exp2f(s1B[0]), eB5 = __builtin_amdgcn_exp2f(s1B[1]);
    float eB6 = __builtin_amdgcn_exp2f(s1B[2]), eB7 = __builtin_amdgcn_exp2f(s1B[3]);
    union { short8 s8; uint4 u4; } ptA, ptB;
    ptA.u4.x = pk2(eA0, eA1); ptA.u4.y = pk2(eA2, eA3);
    ptA.u4.z = pk2(eA4, eA5); ptA.u4.w = pk2(eA6, eA7);
    ptB.u4.x = pk2(eB0, eB1); ptB.u4.y = pk2(eB2, eB3);
    ptB.u4.z = pk2(eB4, eB5); ptB.u4.w = pk2(eB6, eB7);
    __builtin_amdgcn_s_setprio(1);
    esA4 = __builtin_amdgcn_mfma_f32_16x16x32_bf16(ones, ptA.s8, esA4, 0, 0, 0);
    esB4 = __builtin_amdgcn_mfma_f32_16x16x32_bf16(ones, ptB.s8, esB4, 0, 0, 0);
    faccA[0] = __builtin_amdgcn_mfma_f32_16x16x32_bf16(vf0, ptA.s8, faccA[0], 0, 0, 0);
    faccB[0] = __builtin_amdgcn_mfma_f32_16x16x32_bf16(vf0, ptB.s8, faccB[0], 0, 0, 0);
    faccA[1] = __builtin_amdgcn_mfma_f32_16x16x32_bf16(vf1, ptA.s8, faccA[1], 0, 0, 0);
    faccB[1] = __builtin_amdgcn_mfma_f32_16x16x32_bf16(vf1, ptB.s8, faccB[1], 0, 0, 0);
    faccA[2] = __builtin_amdgcn_mfma_f32_16x16x32_bf16(vf2, ptA.s8, faccA[2], 0, 0, 0);
    faccB[2] = __builtin_amdgcn_mfma_f32_16x16x32_bf16(vf2, ptB.s8, faccB[2], 0, 0, 0);
    faccA[3] = __builtin_amdgcn_mfma_f32_16x16x32_bf16(vf3, ptA.s8, faccA[3], 0, 0, 0);
    faccB[3] = __builtin_amdgcn_mfma_f32_16x16x32_bf16(vf3, ptB.s8, faccB[3], 0, 0, 0);
    __builtin_amdgcn_s_setprio(0);
  }

  // ---- pair combine: mh=1 waves dump, mh=0 waves finalize into featlds
  if (mh == 1) {
#pragma unroll
    for (int kt = 0; kt < 4; kt++)
#pragma unroll
      for (int r = 0; r < 4; r++) {
        sfacc[nh][l][4 * kt + r]      = faccA[kt][r];
        sfacc[nh][l][16 + 4 * kt + r] = faccB[kt][r];
      }
    sfacc[nh][l][32] = esA4[0];
    sfacc[nh][l][33] = esB4[0];
  }
  __syncthreads();
  if (mh == 0) {
    float teA = esA4[0] + sfacc[nh][l][32];
    float teB = esB4[0] + sfacc[nh][l][33];
#pragma unroll
    for (int kt = 0; kt < 4; kt++)
#pragma unroll
      for (int r = 0; r < 4; r++) {
        faccA[kt][r] += sfacc[nh][l][4 * kt + r];
        faccB[kt][r] += sfacc[nh][l][16 + 4 * kt + r];
      }
    float invA = 1.0f / teA, invB = 1.0f / teB;
    int na = 32 * nh + n16, nbw = na + 16;
    char* rowa = (char*)&featlds[0][0] + na * 128;
    char* rowb = (char*)&featlds[0][0] + nbw * 128;
    int rxa = (na & 7) << 4, rxb = (nbw & 7) << 4;
#pragma unroll
    for (int kt = 0; kt < 4; kt++) {
      uint2 ua, ub;
      ua.x = pk2(faccA[kt][0] * invA, faccA[kt][1] * invA);
      ua.y = pk2(faccA[kt][2] * invA, faccA[kt][3] * invA);
      ub.x = pk2(faccB[kt][0] * invB, faccB[kt][1] * invB);
      ub.y = pk2(faccB[kt][2] * invB, faccB[kt][3] * invB);
      int cb = (16 * kt + 4 * g) * 2;
      *(uint2*)(rowa + (cb ^ rxa)) = ua;
      *(uint2*)(rowb + (cb ^ rxb)) = ub;
    }
  }
  __syncthreads();

  // ---- fused outproj: out[128oc][64n] = gamma*(wa@feat + ba) + x
  short8 bfr[4][2];
#pragma unroll
  for (int nt = 0; nt < 4; nt++) {
    int nl = 16 * nt + n16;
    char* rowp = (char*)&featlds[0][0] + nl * 128;
    int rx = (nl & 7) << 4;
#pragma unroll
    for (int s = 0; s < 2; s++)
      bfr[nt][s] = *(const short8*)(rowp + (((32 * s + 8 * g) * 2) ^ rx));
  }
  float g0 = gamma[0];
#pragma unroll
  for (int ti = 0; ti < 2; ti++) {
    int ot = 2 * w + ti;
    short8 af0 = *(const short8*)&waB[(size_t)(16 * ot + n16) * NCV + 8 * g];
    short8 af1 = *(const short8*)&waB[(size_t)(16 * ot + n16) * NCV + 32 + 8 * g];
    float b0 = ba[16 * ot + 4 * g + 0];
    float b1 = ba[16 * ot + 4 * g + 1];
    float b2 = ba[16 * ot + 4 * g + 2];
    float b3 = ba[16 * ot + 4 * g + 3];
#pragma unroll
    for (int nt = 0; nt < 4; nt++) {
      f32x4 c0 = {b0, b1, b2, b3};
      c0 = __builtin_amdgcn_mfma_f32_16x16x32_bf16(af0, bfr[nt][0], c0, 0, 0, 0);
      c0 = __builtin_amdgcn_mfma_f32_16x16x32_bf16(af1, bfr[nt][1], c0, 0, 0, 0);
#pragma unroll
      for (int r = 0; r < 4; r++) {
        size_t idx = ((size_t)b * NC + 16 * ot + 4 * g + r) * NHW + n0 + 16 * nt + n16;
        out[idx] = g0 * c0[r] + x[idx];
      }
    }
  }
}

extern "C" void kernel_launch(void* const* d_in, const int* in_sizes, int n_in,
                              void* d_out, int out_size, void* d_ws, size_t ws_size,
                              hipStream_t stream) {
  const float* x     = (const float*)d_in[0];
  const float* wq    = (const float*)d_in[1];
  const float* bq    = (const float*)d_in[2];
  const float* wk    = (const float*)d_in[3];
  const float* bk    = (const float*)d_in[4];
  const float* wv    = (const float*)d_in[5];
  const float* bv    = (const float*)d_in[6];
  const float* wa    = (const float*)d_in[7];
  const float* ba    = (const float*)d_in[8];
  const float* gamma = (const float*)d_in[9];
  float* out = (float*)d_out;

  unsigned short* kT  = (unsigned short*)d_ws;                 // 16*1024*16  = 512 KB
  unsigned short* vv  = kT + (size_t)NB * NHWP * NCQ;          // 16*64*1024  = 2 MB (tiled)
  unsigned short* wqB = vv + (size_t)NB * NCV * NHWP;          // 16*128      = 4 KB
  unsigned short* waB = wqB + (size_t)NCQ * NC;                // 128*64      = 16 KB

  projkv_kernel<<<NB * 5 * 16, 256, 0, stream>>>(x, wk, bk, wv, bv, wq, wa,
                                                 kT, vv, wqB, waB);
  attn_kernel  <<<NB * 64,     256, 0, stream>>>(x, wqB, bq, kT, vv, waB, ba,
                                                 gamma, out);
}